// Round 1
// baseline (264.387 us; speedup 1.0000x reference)
//
#include <hip/hip_runtime.h>

#define N_NODES 50000
#define N_EDGES 800000
#define DIM 128
#define OUTD 47
#define NBK 196                          // dst buckets of 256 nodes
#define EPB 4096                         // edges per histogram/bin block
#define NBIN ((N_EDGES + EPB - 1) / EPB) // 196
#define XCVT_NB (N_NODES * DIM / 8 / 256) // 3125 blocks, 8 elems/thread
#define WCVT_NB (DIM + DIM + 48)         // 304 weight-row blocks

typedef __attribute__((ext_vector_type(8))) short v8s;
typedef __attribute__((ext_vector_type(8))) unsigned short v8u;
typedef __attribute__((ext_vector_type(4))) float v4f;
typedef __attribute__((ext_vector_type(2))) float v2f;

static __device__ __forceinline__ unsigned short f2bf(float f) {
    union { float f; unsigned int u; } v; v.f = f;
    unsigned int x = v.u;
    return (unsigned short)((x + 0x7fffu + ((x >> 16) & 1u)) >> 16); // RNE
}
static __device__ __forceinline__ unsigned char f2fp8(float f) {
    unsigned int pk = __builtin_amdgcn_cvt_pk_fp8_f32(f, f, 0, false);
    return (unsigned char)(pk & 0xffu);
}

// ---------------- prep: x->bf16+fp8 | per-block bucket hist partials | weight cvt ----------------
// One kernel, three block ranges. No global atomics anywhere (round-6 lesson: 473 us).
__global__ __launch_bounds__(256) void k_prep(const float* __restrict__ x,
                                              unsigned short* __restrict__ xb,
                                              unsigned int* __restrict__ x8,
                                              const int* __restrict__ dst,
                                              int* __restrict__ parts,
                                              const float* __restrict__ ws1, const float* __restrict__ wn1,
                                              const float* __restrict__ ws2, const float* __restrict__ wn2,
                                              const float* __restrict__ ws3, const float* __restrict__ wn3,
                                              unsigned short* __restrict__ wb1,
                                              unsigned short* __restrict__ wb2,
                                              unsigned short* __restrict__ wb3) {
    __shared__ int hist[NBK];
    const int bx = blockIdx.x, tid = threadIdx.x;
    if (bx < XCVT_NB) {
        int i = bx * 256 + tid; // 8 elems per thread
        float4 v0 = ((const float4*)x)[i * 2];
        float4 v1 = ((const float4*)x)[i * 2 + 1];
        ushort4 o0, o1;
        o0.x = f2bf(v0.x); o0.y = f2bf(v0.y); o0.z = f2bf(v0.z); o0.w = f2bf(v0.w);
        o1.x = f2bf(v1.x); o1.y = f2bf(v1.y); o1.z = f2bf(v1.z); o1.w = f2bf(v1.w);
        ((ushort4*)xb)[i * 2] = o0;
        ((ushort4*)xb)[i * 2 + 1] = o1;
        unsigned int a = __builtin_amdgcn_cvt_pk_fp8_f32(v0.x, v0.y, 0, false);
        a = __builtin_amdgcn_cvt_pk_fp8_f32(v0.z, v0.w, a, true);
        unsigned int b = __builtin_amdgcn_cvt_pk_fp8_f32(v1.x, v1.y, 0, false);
        b = __builtin_amdgcn_cvt_pk_fp8_f32(v1.z, v1.w, b, true);
        uint2 o; o.x = a; o.y = b;
        ((uint2*)x8)[i] = o;
    } else if (bx < XCVT_NB + NBIN) {
        const int j = bx - XCVT_NB;
        for (int i = tid; i < NBK; i += 256) hist[i] = 0;
        __syncthreads();
        const int e0 = j * EPB;
        const int ecnt = min(EPB, N_EDGES - e0);
        for (int r = tid; r < ecnt; r += 256)
            atomicAdd(&hist[dst[e0 + r] >> 8], 1); // LDS only
        __syncthreads();
        for (int i = tid; i < NBK; i += 256) parts[j * NBK + i] = hist[i];
    } else {
        int b2 = bx - XCVT_NB - NBIN; // weight row
        const float *sw, *nw; unsigned short* ob; int j, J;
        if (b2 < DIM)            { sw = ws1; nw = wn1; ob = wb1; j = b2;            J = DIM; }
        else if (b2 < 2 * DIM)   { sw = ws2; nw = wn2; ob = wb2; j = b2 - DIM;      J = DIM; }
        else                     { sw = ws3; nw = wn3; ob = wb3; j = b2 - 2 * DIM;  J = OUTD; }
        int k = tid;
        float v = 0.f;
        if (j < J) v = (k < DIM) ? sw[j * DIM + k] : nw[j * DIM + (k - DIM)];
        ob[j * 256 + k] = f2bf(v);
    }
}

// ---------------- bin: local column-prefix of parts -> bases; place edges (LDS atomics only) ----------------
__global__ __launch_bounds__(256) void k_bin(const int* __restrict__ src,
                                             const int* __restrict__ dst,
                                             const int* __restrict__ parts,
                                             unsigned int* __restrict__ packed) {
    __shared__ int s[256], gb[NBK], cnt[NBK];
    const int t = threadIdx.x;
    const int j = blockIdx.x;
    int ct = 0, cp = 0;
    for (int i = 0; i < NBIN; ++i) {
        int v = (t < NBK) ? parts[i * NBK + t] : 0;
        if (i == j) cp = ct;
        ct += v;
    }
    s[t] = ct;
    __syncthreads();
    for (int off = 1; off < 256; off <<= 1) {
        int u = (t >= off) ? s[t - off] : 0;
        __syncthreads();
        s[t] += u;
        __syncthreads();
    }
    if (t < NBK) { gb[t] = (s[t] - ct) + cp; cnt[t] = 0; } // bucket base + own-block offset
    __syncthreads();
    const int e0 = j * EPB;
    const int ecnt = min(EPB, N_EDGES - e0);
    for (int r = t; r < ecnt; r += 256) {
        int sv = src[e0 + r], d = dst[e0 + r];
        int b = d >> 8;
        int loc = atomicAdd(&cnt[b], 1); // LDS
        packed[gb[b] + loc] = ((unsigned int)sv << 8) | (unsigned int)(d & 255);
    }
}

// ---------------- place: local bucket scan + per-node hist -> row_ptr, scatter src_sorted ----------------
__global__ __launch_bounds__(256) void k_place(const unsigned int* __restrict__ packed,
                                               const int* __restrict__ parts,
                                               int* __restrict__ row_ptr,
                                               int* __restrict__ src_sorted) {
    __shared__ int s[256], baseL[NBK], totL[NBK];
    __shared__ int hist[256], cur[256];
    const int b = blockIdx.x, t = threadIdx.x;
    int ct = 0;
    for (int i = 0; i < NBIN; ++i)
        ct += (t < NBK) ? parts[i * NBK + t] : 0;
    s[t] = ct;
    hist[t] = 0;
    __syncthreads();
    for (int off = 1; off < 256; off <<= 1) {
        int u = (t >= off) ? s[t - off] : 0;
        __syncthreads();
        s[t] += u;
        __syncthreads();
    }
    if (t < NBK) { baseL[t] = s[t] - ct; totL[t] = ct; }
    __syncthreads();
    const int base = baseL[b], cb = totL[b];
    for (int i = t; i < cb; i += 256)
        atomicAdd(&hist[packed[base + i] & 255u], 1); // LDS, ~16 avg per counter
    __syncthreads();
    int v = hist[t];
    s[t] = v;
    __syncthreads();
    for (int off = 1; off < 256; off <<= 1) {
        int u = (t >= off) ? s[t - off] : 0;
        __syncthreads();
        s[t] += u;
        __syncthreads();
    }
    int excl = base + s[t] - v;
    int node = b * 256 + t;
    if (node < N_NODES) row_ptr[node] = excl;
    if (b == NBK - 1 && t == 255) row_ptr[N_NODES] = base + cb; // == N_EDGES
    cur[t] = excl;
    __syncthreads();
    for (int i = t; i < cb; i += 256) {
        unsigned int pkt = packed[base + i];
        int pos = atomicAdd(&cur[pkt & 255u], 1);
        src_sorted[pos] = (int)(pkt >> 8); // lands in this bucket's ~16KB region
    }
}

// ---------------- mean aggregation: 4 nodes/wave, 16 lanes/node split into 2x8-lane halves ----------------
// Each 8-lane half reads a FULL 16B (dwordx4) slice of a DIFFERENT edge's 128B fp8 row:
// one load instruction covers 8 edge-rows (2x the old uint2 scheme). Main loop = 8 edges
// (4 independent 16B loads in flight per lane). Cross-half combine: single shfl_xor(8).
// No LDS -> full occupancy (the gather is latency-bound, lives on wave count + bytes in flight).
static __device__ __forceinline__ void acc16(v2f* acc, uint4 u) {
    acc[0] += __builtin_amdgcn_cvt_pk_f32_fp8(u.x, false);
    acc[1] += __builtin_amdgcn_cvt_pk_f32_fp8(u.x, true);
    acc[2] += __builtin_amdgcn_cvt_pk_f32_fp8(u.y, false);
    acc[3] += __builtin_amdgcn_cvt_pk_f32_fp8(u.y, true);
    acc[4] += __builtin_amdgcn_cvt_pk_f32_fp8(u.z, false);
    acc[5] += __builtin_amdgcn_cvt_pk_f32_fp8(u.z, true);
    acc[6] += __builtin_amdgcn_cvt_pk_f32_fp8(u.w, false);
    acc[7] += __builtin_amdgcn_cvt_pk_f32_fp8(u.w, true);
}

__global__ __launch_bounds__(256) void k_agg16(const unsigned char* __restrict__ h8,
                                               const int* __restrict__ row_ptr,
                                               const int* __restrict__ srcs,
                                               unsigned short* __restrict__ meanb) {
    const int tid = threadIdx.x;
    const int lane = tid & 63, wv = tid >> 6;
    const int g8 = lane & 7;          // 8 lanes span the 128B row, 16B each
    const int sub = (lane >> 3) & 1;  // which edge of a pair this half handles
    const int ns = lane >> 4;         // node slot within wave (4 nodes/wave)
    const int n = blockIdx.x * 16 + wv * 4 + ns;
    const int start = row_ptr[n], end = row_ptr[n + 1]; // uniform per 16-lane group
    v2f acc[8] = {};
    int e = start;
    for (; e + 8 <= end; e += 8) {
        int s0 = srcs[e + sub];
        int s1 = srcs[e + 2 + sub];
        int s2 = srcs[e + 4 + sub];
        int s3 = srcs[e + 6 + sub];
        uint4 u0 = *(const uint4*)(h8 + (size_t)s0 * DIM + g8 * 16);
        uint4 u1 = *(const uint4*)(h8 + (size_t)s1 * DIM + g8 * 16);
        uint4 u2 = *(const uint4*)(h8 + (size_t)s2 * DIM + g8 * 16);
        uint4 u3 = *(const uint4*)(h8 + (size_t)s3 * DIM + g8 * 16);
        acc16(acc, u0); acc16(acc, u1); acc16(acc, u2); acc16(acc, u3);
    }
    if (e + 4 <= end) {
        int s0 = srcs[e + sub];
        int s1 = srcs[e + 2 + sub];
        uint4 u0 = *(const uint4*)(h8 + (size_t)s0 * DIM + g8 * 16);
        uint4 u1 = *(const uint4*)(h8 + (size_t)s1 * DIM + g8 * 16);
        acc16(acc, u0); acc16(acc, u1);
        e += 4;
    }
    if (e + 2 <= end) {
        int s0 = srcs[e + sub];
        uint4 u0 = *(const uint4*)(h8 + (size_t)s0 * DIM + g8 * 16);
        acc16(acc, u0);
        e += 2;
    }
    if (e < end && sub == 0) { // odd leftover edge: even half only
        int s0 = srcs[e];
        uint4 u0 = *(const uint4*)(h8 + (size_t)s0 * DIM + g8 * 16);
        acc16(acc, u0);
    }
    // combine the two 8-lane halves (lane ^ 8 holds the partner edges' partials)
    #pragma unroll
    for (int i = 0; i < 8; ++i) {
        acc[i][0] += __shfl_xor(acc[i][0], 8);
        acc[i][1] += __shfl_xor(acc[i][1], 8);
    }
    int d = end - start;
    float inv = (d > 0) ? 1.f / (float)d : 0.f;
    // lane (g8, sub) writes channels [g8*16 + sub*8, +8)
    // static select (no runtime-indexed register array -> avoids scratch):
    v2f w0 = sub ? acc[4] : acc[0];
    v2f w1 = sub ? acc[5] : acc[1];
    v2f w2 = sub ? acc[6] : acc[2];
    v2f w3 = sub ? acc[7] : acc[3];
    v8u o;
    o[0] = f2bf(w0[0] * inv); o[1] = f2bf(w0[1] * inv);
    o[2] = f2bf(w1[0] * inv); o[3] = f2bf(w1[1] * inv);
    o[4] = f2bf(w2[0] * inv); o[5] = f2bf(w2[1] * inv);
    o[6] = f2bf(w3[0] * inv); o[7] = f2bf(w3[1] * inv);
    *(v8u*)(meanb + (size_t)n * DIM + g8 * 16 + sub * 8) = o;
}

// ---------------- LDS-staged MFMA GEMM (whole K resident, XOR-swizzled) ----------------
template <int JT, int TPW, bool RELU, bool OUTBF>
__global__ __launch_bounds__(256) void k_gemm_lds(const unsigned short* __restrict__ Ab,
                                                  const unsigned short* __restrict__ Mb,
                                                  const unsigned short* __restrict__ Wb,
                                                  const float* __restrict__ bias,
                                                  void* __restrict__ out,
                                                  unsigned char* __restrict__ out8,
                                                  int outdim) {
    __shared__ unsigned short Alds[64 * 256];  // 32 KB
    __shared__ unsigned short Wlds[JT * 256];  // 32 KB (JT=64) / 24 KB (JT=48)
    const int tid = threadIdx.x;
    const int m0 = blockIdx.x * 64;
    const int j0 = blockIdx.y * JT;
    v8u ar[8];
    #pragma unroll
    for (int i = 0; i < 8; ++i) {
        int t = tid + 256 * i;
        int row = t >> 5, ch = t & 31;
        int node = m0 + row; if (node >= N_NODES) node = N_NODES - 1;
        const unsigned short* s = (ch < 16) ? (Ab + (size_t)node * DIM + ch * 8)
                                            : (Mb + (size_t)node * DIM + (ch - 16) * 8);
        ar[i] = *(const v8u*)s;
    }
    constexpr int WI = (JT * 32 + 255) / 256;
    v8u wr[WI];
    #pragma unroll
    for (int i = 0; i < WI; ++i) {
        int t = tid + 256 * i;
        if (t < JT * 32) {
            int row = t >> 5, ch = t & 31;
            wr[i] = *(const v8u*)(Wb + (size_t)(j0 + row) * 256 + ch * 8);
        }
    }
    #pragma unroll
    for (int i = 0; i < 8; ++i) {
        int t = tid + 256 * i;
        int row = t >> 5, ch = t & 31;
        *(v8u*)(Alds + row * 256 + ((ch * 8) ^ ((row & 7) * 8))) = ar[i];
    }
    #pragma unroll
    for (int i = 0; i < WI; ++i) {
        int t = tid + 256 * i;
        if (t < JT * 32) {
            int row = t >> 5, ch = t & 31;
            *(v8u*)(Wlds + row * 256 + ((ch * 8) ^ ((row & 7) * 8))) = wr[i];
        }
    }
    __syncthreads();
    const int lane = tid & 63, wv = tid >> 6;
    const int m = lane & 15, qd = lane >> 4;
    const int arow = wv * 16 + m;
    v4f acc[TPW] = {};
    #pragma unroll
    for (int c = 0; c < 8; ++c) {
        const int koff = c * 32 + qd * 8;
        v8s af = *(const v8s*)(Alds + arow * 256 + (koff ^ ((arow & 7) * 8)));
        #pragma unroll
        for (int t = 0; t < TPW; ++t) {
            int wrow = t * 16 + m;
            v8s wf = *(const v8s*)(Wlds + wrow * 256 + (koff ^ ((wrow & 7) * 8)));
            acc[t] = __builtin_amdgcn_mfma_f32_16x16x32_bf16(af, wf, acc[t], 0, 0, 0);
        }
    }
    #pragma unroll
    for (int t = 0; t < TPW; ++t) {
        int col = j0 + t * 16 + m;
        bool colok = (col < outdim);
        float bv = colok ? bias[col] : 0.f;
        #pragma unroll
        for (int r = 0; r < 4; ++r) {
            int nrow = m0 + wv * 16 + qd * 4 + r;
            if (colok && nrow < N_NODES) {
                float v = acc[t][r] + bv;
                if (RELU) v = fmaxf(v, 0.f);
                size_t idx = (size_t)nrow * outdim + col;
                if (OUTBF) {
                    ((unsigned short*)out)[idx] = f2bf(v);
                    out8[idx] = f2fp8(v);
                } else {
                    ((float*)out)[idx] = v;
                }
            }
        }
    }
}

extern "C" void kernel_launch(void* const* d_in, const int* in_sizes, int n_in,
                              void* d_out, int out_size, void* d_ws, size_t ws_size,
                              hipStream_t stream) {
    const float* x   = (const float*)d_in[0];
    const int*   src = (const int*)d_in[1];
    const int*   dst = (const int*)d_in[2];
    const float* ws1 = (const float*)d_in[3];
    const float* wn1 = (const float*)d_in[4];
    const float* b1  = (const float*)d_in[5];
    const float* ws2 = (const float*)d_in[6];
    const float* wn2 = (const float*)d_in[7];
    const float* b2  = (const float*)d_in[8];
    const float* ws3 = (const float*)d_in[9];
    const float* wn3 = (const float*)d_in[10];
    const float* b3  = (const float*)d_in[11];

    char* p = (char*)d_ws;
    auto alloc = [&](size_t bytes) { char* r = p; p += (bytes + 255) & ~(size_t)255; return r; };
    int*   row_ptr = (int*)alloc((size_t)(N_NODES + 1) * 4);
    int*   srcs    = (int*)alloc((size_t)N_EDGES * 4);
    unsigned int* packed = (unsigned int*)alloc((size_t)N_EDGES * 4);
    int*   parts   = (int*)alloc((size_t)NBIN * NBK * 4);
    unsigned short* xb    = (unsigned short*)alloc((size_t)N_NODES * DIM * 2);
    unsigned short* meanb = (unsigned short*)alloc((size_t)N_NODES * DIM * 2);
    unsigned short* h1b   = (unsigned short*)alloc((size_t)N_NODES * DIM * 2);
    unsigned short* h2b   = (unsigned short*)alloc((size_t)N_NODES * DIM * 2);
    unsigned char*  h8    = (unsigned char*)alloc((size_t)N_NODES * DIM);
    unsigned short* wb1 = (unsigned short*)alloc((size_t)DIM * 256 * 2);
    unsigned short* wb2 = (unsigned short*)alloc((size_t)DIM * 256 * 2);
    unsigned short* wb3 = (unsigned short*)alloc((size_t)48 * 256 * 2);

    // 1: conversions + bucket hist partials (no global atomics, no memsets)
    k_prep<<<XCVT_NB + NBIN + WCVT_NB, 256, 0, stream>>>(
        x, xb, (unsigned int*)h8, dst, parts,
        ws1, wn1, ws2, wn2, ws3, wn3, wb1, wb2, wb3);
    // 2-3: CSR (bucket prefix recomputed locally in each kernel; no serial scan dispatch)
    k_bin<<<NBIN, 256, 0, stream>>>(src, dst, parts, packed);
    k_place<<<NBK, 256, 0, stream>>>(packed, parts, row_ptr, srcs);

    const int MB = (N_NODES + 63) / 64; // 782
    const int AB = N_NODES / 16;        // 3125

    // layer 1
    k_agg16<<<AB, 256, 0, stream>>>(h8, row_ptr, srcs, meanb);
    k_gemm_lds<64, 4, true, true><<<dim3(MB, 2), 256, 0, stream>>>(xb, meanb, wb1, b1, h1b, h8, DIM);
    // layer 2
    k_agg16<<<AB, 256, 0, stream>>>(h8, row_ptr, srcs, meanb);
    k_gemm_lds<64, 4, true, true><<<dim3(MB, 2), 256, 0, stream>>>(h1b, meanb, wb2, b2, h2b, h8, DIM);
    // layer 3
    k_agg16<<<AB, 256, 0, stream>>>(h8, row_ptr, srcs, meanb);
    k_gemm_lds<48, 3, false, false><<<dim3(MB, 1), 256, 0, stream>>>(h2b, meanb, wb3, b3, d_out, nullptr, OUTD);
}

// Round 3
// 241.497 us; speedup vs baseline: 1.0948x; 1.0948x over previous
//
#include <hip/hip_runtime.h>

#define N_NODES 50000
#define N_EDGES 800000
#define DIM 128
#define OUTD 47
#define NBK 196                          // dst buckets of 256 nodes
#define EPB 4096                         // edges per histogram/bin block
#define NBIN ((N_EDGES + EPB - 1) / EPB) // 196
#define XCVT_NB (N_NODES * DIM / 8 / 256) // 3125 blocks, 8 elems/thread
#define WFNB 19                          // weight-fragment tiles: 8 + 8 + 3

typedef __attribute__((ext_vector_type(8))) short v8s;
typedef __attribute__((ext_vector_type(8))) unsigned short v8u;
typedef __attribute__((ext_vector_type(4))) float v4f;
typedef __attribute__((ext_vector_type(2))) float v2f;

static __device__ __forceinline__ unsigned short f2bf(float f) {
    union { float f; unsigned int u; } v; v.f = f;
    unsigned int x = v.u;
    return (unsigned short)((x + 0x7fffu + ((x >> 16) & 1u)) >> 16); // RNE
}
static __device__ __forceinline__ unsigned char f2fp8(float f) {
    unsigned int pk = __builtin_amdgcn_cvt_pk_fp8_f32(f, f, 0, false);
    return (unsigned char)(pk & 0xffu);
}

// ---------------- prep: x->bf16+fp8 | per-block bucket hist partials | weight fragment cvt ----------------
// Weights are emitted PRE-SWIZZLED into MFMA B-fragment order:
//   frag(t, c): lane l holds W[j = t*16 + (l&15)][k = c*32 + (l>>4)*8 + i], i=0..7 (bf16 x8, 16B)
//   stored at ob[((t*8 + c)*64 + l)*8 + i]  -> a wave's fragment read is 1KB contiguous.
__global__ __launch_bounds__(256) void k_prep(const float* __restrict__ x,
                                              unsigned short* __restrict__ xb,
                                              unsigned int* __restrict__ x8,
                                              const int* __restrict__ dst,
                                              int* __restrict__ parts,
                                              const float* __restrict__ ws1, const float* __restrict__ wn1,
                                              const float* __restrict__ ws2, const float* __restrict__ wn2,
                                              const float* __restrict__ ws3, const float* __restrict__ wn3,
                                              unsigned short* __restrict__ wf1,
                                              unsigned short* __restrict__ wf2,
                                              unsigned short* __restrict__ wf3) {
    __shared__ int hist[NBK];
    const int bx = blockIdx.x, tid = threadIdx.x;
    if (bx < XCVT_NB) {
        int i = bx * 256 + tid; // 8 elems per thread
        float4 v0 = ((const float4*)x)[i * 2];
        float4 v1 = ((const float4*)x)[i * 2 + 1];
        ushort4 o0, o1;
        o0.x = f2bf(v0.x); o0.y = f2bf(v0.y); o0.z = f2bf(v0.z); o0.w = f2bf(v0.w);
        o1.x = f2bf(v1.x); o1.y = f2bf(v1.y); o1.z = f2bf(v1.z); o1.w = f2bf(v1.w);
        ((ushort4*)xb)[i * 2] = o0;
        ((ushort4*)xb)[i * 2 + 1] = o1;
        unsigned int a = __builtin_amdgcn_cvt_pk_fp8_f32(v0.x, v0.y, 0, false);
        a = __builtin_amdgcn_cvt_pk_fp8_f32(v0.z, v0.w, a, true);
        unsigned int b = __builtin_amdgcn_cvt_pk_fp8_f32(v1.x, v1.y, 0, false);
        b = __builtin_amdgcn_cvt_pk_fp8_f32(v1.z, v1.w, b, true);
        uint2 o; o.x = a; o.y = b;
        ((uint2*)x8)[i] = o;
    } else if (bx < XCVT_NB + NBIN) {
        const int j = bx - XCVT_NB;
        for (int i = tid; i < NBK; i += 256) hist[i] = 0;
        __syncthreads();
        const int e0 = j * EPB;
        const int ecnt = min(EPB, N_EDGES - e0);
        for (int r = tid; r < ecnt; r += 256)
            atomicAdd(&hist[dst[e0 + r] >> 8], 1); // LDS only
        __syncthreads();
        for (int i = tid; i < NBK; i += 256) parts[j * NBK + i] = hist[i];
    } else {
        int b2 = bx - XCVT_NB - NBIN; // fragment tile
        const float *sw, *nw; unsigned short* ob; int t, J;
        if (b2 < 8)       { sw = ws1; nw = wn1; ob = wf1; t = b2;      J = DIM; }
        else if (b2 < 16) { sw = ws2; nw = wn2; ob = wf2; t = b2 - 8;  J = DIM; }
        else              { sw = ws3; nw = wn3; ob = wf3; t = b2 - 16; J = OUTD; }
        const int lane = tid & 63, cp = tid >> 6;
        const int j = t * 16 + (lane & 15);
        const int kb = (lane >> 4) * 8;
        #pragma unroll
        for (int c2 = 0; c2 < 2; ++c2) {
            int c = cp * 2 + c2;
            int k0 = c * 32 + kb;
            v8u o;
            #pragma unroll
            for (int i = 0; i < 8; ++i) {
                int k = k0 + i;
                float v = 0.f;
                if (j < J) v = (k < DIM) ? sw[j * DIM + k] : nw[j * DIM + (k - DIM)];
                o[i] = f2bf(v);
            }
            *(v8u*)(ob + ((size_t)((t * 8 + c) * 64 + lane)) * 8) = o;
        }
    }
}

// ---------------- bin: local column-prefix of parts -> bases; place edges (LDS atomics only) ----------------
__global__ __launch_bounds__(256) void k_bin(const int* __restrict__ src,
                                             const int* __restrict__ dst,
                                             const int* __restrict__ parts,
                                             unsigned int* __restrict__ packed) {
    __shared__ int s[256], gb[NBK], cnt[NBK];
    const int t = threadIdx.x;
    const int j = blockIdx.x;
    int ct = 0, cp = 0;
    for (int i = 0; i < NBIN; ++i) {
        int v = (t < NBK) ? parts[i * NBK + t] : 0;
        if (i == j) cp = ct;
        ct += v;
    }
    s[t] = ct;
    __syncthreads();
    for (int off = 1; off < 256; off <<= 1) {
        int u = (t >= off) ? s[t - off] : 0;
        __syncthreads();
        s[t] += u;
        __syncthreads();
    }
    if (t < NBK) { gb[t] = (s[t] - ct) + cp; cnt[t] = 0; } // bucket base + own-block offset
    __syncthreads();
    const int e0 = j * EPB;
    const int ecnt = min(EPB, N_EDGES - e0);
    for (int r = t; r < ecnt; r += 256) {
        int sv = src[e0 + r], d = dst[e0 + r];
        int b = d >> 8;
        int loc = atomicAdd(&cnt[b], 1); // LDS
        packed[gb[b] + loc] = ((unsigned int)sv << 8) | (unsigned int)(d & 255);
    }
}

// ---------------- place: local bucket scan + per-node hist -> row_ptr, scatter src_sorted ----------------
__global__ __launch_bounds__(256) void k_place(const unsigned int* __restrict__ packed,
                                               const int* __restrict__ parts,
                                               int* __restrict__ row_ptr,
                                               int* __restrict__ src_sorted) {
    __shared__ int s[256], baseL[NBK], totL[NBK];
    __shared__ int hist[256], cur[256];
    const int b = blockIdx.x, t = threadIdx.x;
    int ct = 0;
    for (int i = 0; i < NBIN; ++i)
        ct += (t < NBK) ? parts[i * NBK + t] : 0;
    s[t] = ct;
    hist[t] = 0;
    __syncthreads();
    for (int off = 1; off < 256; off <<= 1) {
        int u = (t >= off) ? s[t - off] : 0;
        __syncthreads();
        s[t] += u;
        __syncthreads();
    }
    if (t < NBK) { baseL[t] = s[t] - ct; totL[t] = ct; }
    __syncthreads();
    const int base = baseL[b], cb = totL[b];
    for (int i = t; i < cb; i += 256)
        atomicAdd(&hist[packed[base + i] & 255u], 1); // LDS, ~16 avg per counter
    __syncthreads();
    int v = hist[t];
    s[t] = v;
    __syncthreads();
    for (int off = 1; off < 256; off <<= 1) {
        int u = (t >= off) ? s[t - off] : 0;
        __syncthreads();
        s[t] += u;
        __syncthreads();
    }
    int excl = base + s[t] - v;
    int node = b * 256 + t;
    if (node < N_NODES) row_ptr[node] = excl;
    if (b == NBK - 1 && t == 255) row_ptr[N_NODES] = base + cb; // == N_EDGES
    cur[t] = excl;
    __syncthreads();
    for (int i = t; i < cb; i += 256) {
        unsigned int pkt = packed[base + i];
        int pos = atomicAdd(&cur[pkt & 255u], 1);
        src_sorted[pos] = (int)(pkt >> 8); // lands in this bucket's ~16KB region
    }
}

// ---------------- fused layer: self-load + mean-aggregate -> LDS A-tile, then MFMA GEMM ----------------
// 64 nodes/block, 256 threads, LDS = 32 KB only (A tile) -> 4 blocks/CU for gather TLP.
// Weights are NOT staged: read as pre-swizzled fragments straight from L2 (64KB, hot everywhere).
// meanb round-trip eliminated; fp8 gather table double-buffered (g8 in, out8 out) to avoid the
// read-while-write race the fusion would otherwise create.
static __device__ __forceinline__ void acc16(v2f* acc, uint4 u) {
    acc[0] += __builtin_amdgcn_cvt_pk_f32_fp8(u.x, false);
    acc[1] += __builtin_amdgcn_cvt_pk_f32_fp8(u.x, true);
    acc[2] += __builtin_amdgcn_cvt_pk_f32_fp8(u.y, false);
    acc[3] += __builtin_amdgcn_cvt_pk_f32_fp8(u.y, true);
    acc[4] += __builtin_amdgcn_cvt_pk_f32_fp8(u.z, false);
    acc[5] += __builtin_amdgcn_cvt_pk_f32_fp8(u.z, true);
    acc[6] += __builtin_amdgcn_cvt_pk_f32_fp8(u.w, false);
    acc[7] += __builtin_amdgcn_cvt_pk_f32_fp8(u.w, true);
}

template <int NT, bool RELU, bool OUTBF>
__global__ __launch_bounds__(256, 4) void k_layer(const unsigned short* __restrict__ Ab,
                                                  const unsigned char* __restrict__ g8,
                                                  const int* __restrict__ row_ptr,
                                                  const int* __restrict__ srcs,
                                                  const unsigned short* __restrict__ Wf,
                                                  const float* __restrict__ bias,
                                                  void* __restrict__ out,
                                                  unsigned char* __restrict__ out8,
                                                  int outdim) {
    __shared__ unsigned short Alds[64 * 256]; // 32 KB: [row][0..128)=self, [128..256)=mean, XOR-swizzled
    const int tid = threadIdx.x;
    const int m0 = blockIdx.x * 64;
    // ---- self half -> LDS ----
    #pragma unroll
    for (int i = 0; i < 4; ++i) {
        int t = tid + 256 * i;           // 0..1023
        int row = t >> 4, ch = t & 15;   // 64 rows x 16 chunks of 8 shorts
        int node = m0 + row; if (node >= N_NODES) node = N_NODES - 1;
        v8u v = *(const v8u*)(Ab + (size_t)node * DIM + ch * 8);
        *(v8u*)(Alds + row * 256 + ((ch * 8) ^ ((row & 7) * 8))) = v;
    }
    // ---- mean half: gather fp8 rows, 4 nodes per wave-pass, 2x8-lane halves per node ----
    const int lane = tid & 63, wv = tid >> 6;
    const int gg = lane & 7;          // 8 lanes span the 128B row, 16B each
    const int sub = (lane >> 3) & 1;  // which edge of a pair this half handles
    const int ns = lane >> 4;         // node slot within wave
    for (int pass = 0; pass < 4; ++pass) {
        const int row = wv * 16 + pass * 4 + ns; // 0..63
        const int n = m0 + row;
        int start = 0, end = 0;
        if (n < N_NODES) { start = row_ptr[n]; end = row_ptr[n + 1]; }
        v2f ga[8] = {};
        int e = start;
        for (; e + 8 <= end; e += 8) {
            int s0 = srcs[e + sub];
            int s1 = srcs[e + 2 + sub];
            int s2 = srcs[e + 4 + sub];
            int s3 = srcs[e + 6 + sub];
            uint4 u0 = *(const uint4*)(g8 + (size_t)s0 * DIM + gg * 16);
            uint4 u1 = *(const uint4*)(g8 + (size_t)s1 * DIM + gg * 16);
            uint4 u2 = *(const uint4*)(g8 + (size_t)s2 * DIM + gg * 16);
            uint4 u3 = *(const uint4*)(g8 + (size_t)s3 * DIM + gg * 16);
            acc16(ga, u0); acc16(ga, u1); acc16(ga, u2); acc16(ga, u3);
        }
        if (e + 4 <= end) {
            int s0 = srcs[e + sub];
            int s1 = srcs[e + 2 + sub];
            uint4 u0 = *(const uint4*)(g8 + (size_t)s0 * DIM + gg * 16);
            uint4 u1 = *(const uint4*)(g8 + (size_t)s1 * DIM + gg * 16);
            acc16(ga, u0); acc16(ga, u1);
            e += 4;
        }
        if (e + 2 <= end) {
            int s0 = srcs[e + sub];
            uint4 u0 = *(const uint4*)(g8 + (size_t)s0 * DIM + gg * 16);
            acc16(ga, u0);
            e += 2;
        }
        if (e < end && sub == 0) { // odd leftover edge: even half only
            int s0 = srcs[e];
            uint4 u0 = *(const uint4*)(g8 + (size_t)s0 * DIM + gg * 16);
            acc16(ga, u0);
        }
        #pragma unroll
        for (int i = 0; i < 8; ++i) {
            ga[i][0] += __shfl_xor(ga[i][0], 8);
            ga[i][1] += __shfl_xor(ga[i][1], 8);
        }
        int d = end - start;
        float inv = (d > 0) ? 1.f / (float)d : 0.f;
        v2f w0 = sub ? ga[4] : ga[0];
        v2f w1 = sub ? ga[5] : ga[1];
        v2f w2 = sub ? ga[6] : ga[2];
        v2f w3 = sub ? ga[7] : ga[3];
        v8u o;
        o[0] = f2bf(w0[0] * inv); o[1] = f2bf(w0[1] * inv);
        o[2] = f2bf(w1[0] * inv); o[3] = f2bf(w1[1] * inv);
        o[4] = f2bf(w2[0] * inv); o[5] = f2bf(w2[1] * inv);
        o[6] = f2bf(w3[0] * inv); o[7] = f2bf(w3[1] * inv);
        *(v8u*)(Alds + row * 256 + ((DIM + gg * 16 + sub * 8) ^ ((row & 7) * 8))) = o;
    }
    __syncthreads();
    // ---- MFMA: A from LDS, W fragments streamed from L2 (1KB coalesced per wave-load) ----
    const int m = lane & 15, qd = lane >> 4;
    const int arow = wv * 16 + m;
    v4f acc[NT] = {};
    #pragma unroll
    for (int c = 0; c < 8; ++c) {
        const int koff = c * 32 + qd * 8;
        v8s af = *(const v8s*)(Alds + arow * 256 + (koff ^ ((arow & 7) * 8)));
        #pragma unroll
        for (int t = 0; t < NT; ++t) {
            v8s wf = *(const v8s*)(Wf + ((size_t)((t * 8 + c) * 64 + lane)) * 8);
            acc[t] = __builtin_amdgcn_mfma_f32_16x16x32_bf16(af, wf, acc[t], 0, 0, 0);
        }
    }
    // ---- epilogue ----
    #pragma unroll
    for (int t = 0; t < NT; ++t) {
        int col = t * 16 + m;
        bool colok = (col < outdim);
        float bv = colok ? bias[col] : 0.f;
        #pragma unroll
        for (int r = 0; r < 4; ++r) {
            int nrow = m0 + wv * 16 + qd * 4 + r;
            if (colok && nrow < N_NODES) {
                float v = acc[t][r] + bv;
                if (RELU) v = fmaxf(v, 0.f);
                size_t idx = (size_t)nrow * outdim + col;
                if (OUTBF) {
                    ((unsigned short*)out)[idx] = f2bf(v);
                    out8[idx] = f2fp8(v);
                } else {
                    ((float*)out)[idx] = v;
                }
            }
        }
    }
}

extern "C" void kernel_launch(void* const* d_in, const int* in_sizes, int n_in,
                              void* d_out, int out_size, void* d_ws, size_t ws_size,
                              hipStream_t stream) {
    const float* x   = (const float*)d_in[0];
    const int*   src = (const int*)d_in[1];
    const int*   dst = (const int*)d_in[2];
    const float* ws1 = (const float*)d_in[3];
    const float* wn1 = (const float*)d_in[4];
    const float* b1  = (const float*)d_in[5];
    const float* ws2 = (const float*)d_in[6];
    const float* wn2 = (const float*)d_in[7];
    const float* b2  = (const float*)d_in[8];
    const float* ws3 = (const float*)d_in[9];
    const float* wn3 = (const float*)d_in[10];
    const float* b3  = (const float*)d_in[11];

    char* p = (char*)d_ws;
    auto alloc = [&](size_t bytes) { char* r = p; p += (bytes + 255) & ~(size_t)255; return r; };
    int*   row_ptr = (int*)alloc((size_t)(N_NODES + 1) * 4);
    int*   srcs    = (int*)alloc((size_t)N_EDGES * 4);
    unsigned int* packed = (unsigned int*)alloc((size_t)N_EDGES * 4);
    int*   parts   = (int*)alloc((size_t)NBIN * NBK * 4);
    unsigned short* xb  = (unsigned short*)alloc((size_t)N_NODES * DIM * 2);
    unsigned short* h1b = (unsigned short*)alloc((size_t)N_NODES * DIM * 2);
    unsigned short* h2b = (unsigned short*)alloc((size_t)N_NODES * DIM * 2);
    unsigned char*  h8a = (unsigned char*)alloc((size_t)N_NODES * DIM);
    unsigned char*  h8b = (unsigned char*)alloc((size_t)N_NODES * DIM);
    unsigned short* wf1 = (unsigned short*)alloc((size_t)8 * 8 * 64 * 8 * 2);
    unsigned short* wf2 = (unsigned short*)alloc((size_t)8 * 8 * 64 * 8 * 2);
    unsigned short* wf3 = (unsigned short*)alloc((size_t)3 * 8 * 64 * 8 * 2);

    // 1: conversions + bucket hist partials (no global atomics, no memsets)
    k_prep<<<XCVT_NB + NBIN + WFNB, 256, 0, stream>>>(
        x, xb, (unsigned int*)h8a, dst, parts,
        ws1, wn1, ws2, wn2, ws3, wn3, wf1, wf2, wf3);
    // 2-3: CSR (bucket prefix recomputed locally in each kernel; no serial scan dispatch)
    k_bin<<<NBIN, 256, 0, stream>>>(src, dst, parts, packed);
    k_place<<<NBK, 256, 0, stream>>>(packed, parts, row_ptr, srcs);

    const int MB = (N_NODES + 63) / 64; // 782

    // fused layers: agg + GEMM in one kernel each; fp8 table ping-pongs h8a <-> h8b
    k_layer<8, true, true><<<MB, 256, 0, stream>>>(xb,  h8a, row_ptr, srcs, wf1, b1, h1b, h8b, DIM);
    k_layer<8, true, true><<<MB, 256, 0, stream>>>(h1b, h8b, row_ptr, srcs, wf2, b2, h2b, h8a, DIM);
    k_layer<3, false, false><<<MB, 256, 0, stream>>>(h2b, h8a, row_ptr, srcs, wf3, b3, d_out, nullptr, OUTD);
}